// Round 3
// baseline (1718.496 us; speedup 1.0000x reference)
//
#include <hip/hip_runtime.h>
#include <hip/hip_bf16.h>

typedef _Float16 half2_t __attribute__((ext_vector_type(2)));
typedef _Float16 f16x8   __attribute__((ext_vector_type(8)));
typedef float    f32x4   __attribute__((ext_vector_type(4)));
typedef unsigned short u16;
typedef unsigned int   u32;

#define N_NODES 65536
#define IN_DIM  256
#define HIDDEN  256
#define G3      768     // 3*HIDDEN gate rows
#define NGRAPH  128

__device__ __forceinline__ float sigf(float x)    { return 1.f / (1.f + __expf(-x)); }
__device__ __forceinline__ float tanhfast(float x){ return 2.f / (1.f + __expf(-2.f * x)) - 1.f; }

// ---- per-graph starts via binary search on sorted batch (int32/int64 autodetect) ----
__global__ void k_starts(const int* __restrict__ batch, int* __restrict__ starts, int n, int ngraph) {
    int g = blockIdx.x * blockDim.x + threadIdx.x;
    if (g > ngraph) return;
    int stride = (batch[n - 1] == 0) ? 2 : 1;
    if (g == ngraph) { starts[g] = n; return; }
    int lo = 0, hi = n;
    while (lo < hi) { int mid = (lo + hi) >> 1; if (batch[(size_t)mid * stride] < g) lo = mid + 1; else hi = mid; }
    starts[g] = lo;
}

// ---- f32 -> f16 elementwise (n multiple of 8) ----
__global__ void k_cvt8(const float* __restrict__ s, u16* __restrict__ d, int n) {
    int t = blockIdx.x * 256 + threadIdx.x;
    int i = t * 8;
    if (i >= n) return;
    float4 a = ((const float4*)(s + i))[0];
    float4 b = ((const float4*)(s + i))[1];
    f16x8 o;
    o[0] = (_Float16)a.x; o[1] = (_Float16)a.y; o[2] = (_Float16)a.z; o[3] = (_Float16)a.w;
    o[4] = (_Float16)b.x; o[5] = (_Float16)b.y; o[6] = (_Float16)b.z; o[7] = (_Float16)b.w;
    *(f16x8*)(d + i) = o;
}

// ---- combined GEMM bias: bih + bhh for r,z gates (rows<512); b_hn stays in k_rec
// (torch GRU: n = tanh(xn + b_in + r*(hn + b_hn)) -- b_hn is inside r*(...))
__global__ void k_bias(const float* __restrict__ bih, const float* __restrict__ bhh, float* __restrict__ o) {
    int i = blockIdx.x * 256 + threadIdx.x;
    if (i < G3) o[i] = bih[i] + (i < 512 ? bhh[i] : 0.f);
}

// ---- W_hh f32 [768][256] -> MFMA A-fragments for k_rec's 8-wave layout.
// frag index = ((wv*6 + t6)*8 + kt)*64 + l  (wv = wave 0..7, t6 = N-tile 0..5,
// kt = k-tile 0..7, l = lane). Lane l holds
// A[row = wv*96 + t6*16 + (l&15)][k = kt*32 + (l>>4)*8 .. +7] as 8 f16 (uint4).
// (layout matches k_gemm's verified 16x16x32 fragment convention)
__global__ void k_swz(const float* __restrict__ W, uint4* __restrict__ out) {
    int t = blockIdx.x * 256 + threadIdx.x;
    if (t >= 24576) return;
    int l = t & 63, kt = (t >> 6) & 7, rest = t >> 9;   // rest = wv*6+t6, 0..47
    int wv = rest / 6, t6 = rest % 6;
    int row = wv * 96 + t6 * 16 + (l & 15);
    int col = kt * 32 + (l >> 4) * 8;
    const float* s = W + row * 256 + col;
    f16x8 o;
#pragma unroll
    for (int q = 0; q < 8; q++) o[q] = (_Float16)s[q];
    out[t] = __builtin_bit_cast(uint4, o);
}

// ---- GEMM: C[M][N] f16 = A[M][K] * B[N][K]^T + bias[N]
// A is f32 (converted during LDS staging) or f16. 128x128 tile per 256-thread
// WG, 4 waves each 64x64 (4x4 of 16x16x32 f16 MFMA).
template <typename AT>
__global__ __launch_bounds__(256) void k_gemm(
    const AT* __restrict__ A, const u16* __restrict__ Bm,
    const float* __restrict__ bias, u16* __restrict__ C,
    int M, int N, int K)
{
    __shared__ u16 As[128 * 40];   // 32 k + 8 pad per row (80B stride, 16B aligned)
    __shared__ u16 Bs[128 * 40];
    const int m0 = blockIdx.y * 128, n0 = blockIdx.x * 128;
    const int t = threadIdx.x;
    const int wave = t >> 6, lane = t & 63;
    const int wm = wave & 1, wn = wave >> 1;
    const int lr = lane & 15, lq = lane >> 4;
    f32x4 acc[4][4] = {};
    const int sr = t >> 1, sp = t & 1;  // staging: 2 threads per row, 16 elems each
    const AT*  gA = A  + (size_t)(m0 + sr) * K + sp * 16;
    const u16* gB = Bm + (size_t)(n0 + sr) * K + sp * 16;
    u16* sA = As + sr * 40 + sp * 16;
    u16* sB = Bs + sr * 40 + sp * 16;
    for (int kt = 0; kt < K; kt += 32) {
        uint4 av0, av1;
        if constexpr (sizeof(AT) == 4) {       // f32 A: load 16 floats, cvt to f16
            float4 a0 = ((const float4*)gA)[0], a1 = ((const float4*)gA)[1];
            float4 a2 = ((const float4*)gA)[2], a3 = ((const float4*)gA)[3];
            f16x8 lo, hi;
            lo[0]=(_Float16)a0.x; lo[1]=(_Float16)a0.y; lo[2]=(_Float16)a0.z; lo[3]=(_Float16)a0.w;
            lo[4]=(_Float16)a1.x; lo[5]=(_Float16)a1.y; lo[6]=(_Float16)a1.z; lo[7]=(_Float16)a1.w;
            hi[0]=(_Float16)a2.x; hi[1]=(_Float16)a2.y; hi[2]=(_Float16)a2.z; hi[3]=(_Float16)a2.w;
            hi[4]=(_Float16)a3.x; hi[5]=(_Float16)a3.y; hi[6]=(_Float16)a3.z; hi[7]=(_Float16)a3.w;
            av0 = __builtin_bit_cast(uint4, lo);
            av1 = __builtin_bit_cast(uint4, hi);
        } else {                               // f16 A: straight 32B
            av0 = ((const uint4*)gA)[0];
            av1 = ((const uint4*)gA)[1];
        }
        uint4 b0 = ((const uint4*)gB)[0], b1 = ((const uint4*)gB)[1];
        gA += 32; gB += 32;
        __syncthreads();
        ((uint4*)sA)[0] = av0; ((uint4*)sA)[1] = av1;
        ((uint4*)sB)[0] = b0;  ((uint4*)sB)[1] = b1;
        __syncthreads();
        f16x8 af[4], bf[4];
#pragma unroll
        for (int i = 0; i < 4; i++)
            af[i] = *(const f16x8*)(As + (wm * 64 + i * 16 + lr) * 40 + lq * 8);
#pragma unroll
        for (int j = 0; j < 4; j++)
            bf[j] = *(const f16x8*)(Bs + (wn * 64 + j * 16 + lr) * 40 + lq * 8);
#pragma unroll
        for (int i = 0; i < 4; i++)
#pragma unroll
            for (int j = 0; j < 4; j++)
                acc[i][j] = __builtin_amdgcn_mfma_f32_16x16x32_f16(af[i], bf[j], acc[i][j], 0, 0, 0);
    }
#pragma unroll
    for (int i = 0; i < 4; i++) {
        int row = m0 + wm * 64 + i * 16 + lq * 4;
#pragma unroll
        for (int j = 0; j < 4; j++) {
            int col = n0 + wn * 64 + j * 16 + lr;
            float bv = bias[col];
#pragma unroll
            for (int rr = 0; rr < 4; rr++) {
                _Float16 v = (_Float16)(acc[i][j][rr] + bv);
                C[(size_t)(row + rr) * N + col] = __builtin_bit_cast(u16, v);
            }
        }
    }
}

// ---- GRU recurrence via MFMA, weights AGPR-resident. One 512-thread WG (8 waves)
// per graph. Wave wv owns 96 gate rows = 6 N-tiles x 8 k-tiles = 48 A-fragments
// = 192 AGPRs, pinned via asm "+a" (R2 post-mortem: fdot2 sources must be
// arch-VGPRs -> 192 regs land in the arch-VGPR ledger -> scheduler bails to
// 112 and spills to scratch, 1.2us/step L2-bound. MFMA A/B operands read AGPRs
// directly on gfx950, so "+a" moves the weights to the AGPR ledger; arch-VGPR
// pressure stays ~40 and nothing spills.)
// B operand = h broadcast into all 16 cols: lane l's B-frag is h[kt*32 +
// (l>>4)*8 .. +7] (same for all col-lanes) = one ds_read_b128 of hpk4. Every
// lane then holds copies of the gate outputs (row=(l>>4)*4+reg, any col);
// col-0 lanes write them to LDS for the finalize.
__global__ __launch_bounds__(512) __attribute__((amdgpu_waves_per_eu(2, 2)))
void k_rec(
    const u16* __restrict__ gx,          // [N_NODES][768] f16 input gates (incl. b_ih + b_hr/b_hz)
    const uint4* __restrict__ wsw,       // MFMA A-frags of f16 W_hh (k_swz layout)
    const float* __restrict__ bhh,       // [768] f32 (only rows 512.. used: b_hn)
    const int*   __restrict__ starts,    // [129]
    u16* __restrict__ hout,              // f16 h [N_NODES][256] (layer 0) or null
    float* __restrict__ out)             // [128][256] f32 mean (layer 1) or null
{
    __shared__ float gates[G3];          // W_hh*h pre-activations (r,z,n stacked)
    __shared__ uint4 hpk4[HIDDEN / 8];   // h packed as 256 f16 (32 uint4)
    const int g = blockIdx.x;
    const int tid = threadIdx.x;
    const int l = tid & 63, wv = tid >> 6;
    const int start = starts[g];
    const int len = starts[g + 1] - start;
    if (tid < HIDDEN / 8) hpk4[tid] = make_uint4(0, 0, 0, 0);
    // load weight A-frags, pin into AGPRs
    f16x8 wA[6][8];
    {
        const uint4* p = wsw + (size_t)wv * 48 * 64 + l;
#pragma unroll
        for (int t6 = 0; t6 < 6; t6++)
#pragma unroll
            for (int kt = 0; kt < 8; kt++) {
                f16x8 v = __builtin_bit_cast(f16x8, p[(t6 * 8 + kt) * 64]);
                asm volatile("" : "+a"(v));
                wA[t6][kt] = v;
            }
    }
    const _Float16* gxr = (const _Float16*)gx + (size_t)start * G3 + (tid & 255);
    u16* hb = hout ? (hout + (size_t)start * HIDDEN + (tid & 255)) : (u16*)nullptr;
    float hp = 0.f, hs = 0.f;
    const float bn = (tid < 256) ? bhh[512 + tid] : 0.f;
    __syncthreads();
    for (int t = 0; t < len; ++t) {
        // issue gx loads at step-top; consumed ~700 cycles later (hidden by MFMA)
        float gr = 0.f, gz = 0.f, gn = 0.f;
        if (tid < 256) {
            const _Float16* p = gxr + (size_t)t * G3;
            gr = (float)p[0]; gz = (float)p[256]; gn = (float)p[512];
        }
        f32x4 acc[6];
#pragma unroll
        for (int t6 = 0; t6 < 6; t6++) acc[t6] = (f32x4){0.f, 0.f, 0.f, 0.f};
#pragma unroll
        for (int kt = 0; kt < 8; kt++) {
            f16x8 b = __builtin_bit_cast(f16x8, hpk4[kt * 4 + (l >> 4)]); // broadcast per 16-lane group
#pragma unroll
            for (int t6 = 0; t6 < 6; t6++)
                acc[t6] = __builtin_amdgcn_mfma_f32_16x16x32_f16(wA[t6][kt], b, acc[t6], 0, 0, 0);
        }
        if ((l & 15) == 0) {               // col-0 lanes hold rows (l>>4)*4 .. +3 of each tile
            int ro = wv * 96 + (l >> 4) * 4;
#pragma unroll
            for (int t6 = 0; t6 < 6; t6++)
                *(f32x4*)&gates[ro + t6 * 16] = acc[t6];
        }
        __syncthreads();
        if (tid < 256) {
            int h = tid;
            float r = sigf(gr + gates[h]);
            float z = sigf(gz + gates[256 + h]);
            float n = tanhfast(gn + r * (gates[512 + h] + bn));
            float hnew = (1.f - z) * n + z * hp;
            hp = hnew; hs += hnew;
            _Float16 ph = (_Float16)hnew;
            u16 pk = __builtin_bit_cast(u16, ph);
            ((u16*)hpk4)[h] = pk;
            if (hb) hb[(u32)t * HIDDEN] = pk;
        }
        __syncthreads();
    }
    if (out && tid < 256) {
        float inv = 1.f / (float)(len > 0 ? len : 1);
        out[g * HIDDEN + tid] = hs * inv;   // f32 output
    }
}

extern "C" void kernel_launch(void* const* d_in, const int* in_sizes, int n_in,
                              void* d_out, int out_size, void* d_ws, size_t ws_size,
                              hipStream_t stream)
{
    const float* x     = (const float*)d_in[0];
    const int*   batch = (const int*)d_in[1];
    const float* Wih0  = (const float*)d_in[2];
    const float* Whh0  = (const float*)d_in[3];
    const float* bih0  = (const float*)d_in[4];
    const float* bhh0  = (const float*)d_in[5];
    const float* Wih1  = (const float*)d_in[6];
    const float* Whh1  = (const float*)d_in[7];
    const float* bih1  = (const float*)d_in[8];
    const float* bhh1  = (const float*)d_in[9];
    float* out = (float*)d_out;

    // Workspace ~135.5 MB
    char* ws = (char*)d_ws;
    size_t o = 0;
    int*   starts = (int*)  (ws + o); o += 4096;
    float* bias0  = (float*)(ws + o); o += 4096;                         // bih0 + bhh0(r,z)
    float* bias1  = (float*)(ws + o); o += 4096;                         // bih1 + bhh1(r,z)
    u16*   wi0    = (u16*)  (ws + o); o += (size_t)G3 * IN_DIM * 2;      // 384 KB (f16 W_ih0)
    u16*   wi1    = (u16*)  (ws + o); o += (size_t)G3 * HIDDEN * 2;     // 384 KB (f16 W_ih1)
    uint4* wsw0   = (uint4*)(ws + o); o += (size_t)G3 * HIDDEN * 2;     // 384 KB
    uint4* wsw1   = (uint4*)(ws + o); o += (size_t)G3 * HIDDEN * 2;     // 384 KB
    u16*   h0     = (u16*)  (ws + o); o += (size_t)N_NODES * HIDDEN * 2; // 33.5 MB (f16)
    u16*   gxbuf  = (u16*)  (ws + o); o += (size_t)N_NODES * G3 * 2;     // 100.7 MB (f16, reused)

    k_starts<<<1, 256, 0, stream>>>(batch, starts, N_NODES, NGRAPH);
    k_bias<<<3, 256, 0, stream>>>(bih0, bhh0, bias0);
    k_bias<<<3, 256, 0, stream>>>(bih1, bhh1, bias1);
    k_cvt8<<<96, 256, 0, stream>>>(Wih0, wi0, G3 * IN_DIM);
    k_cvt8<<<96, 256, 0, stream>>>(Wih1, wi1, G3 * HIDDEN);
    k_swz<<<96, 256, 0, stream>>>(Whh0, wsw0);
    k_swz<<<96, 256, 0, stream>>>(Whh1, wsw1);

    // layer 0: gx0 = x*Wih0^T + bias0 (A staged f32->f16); rec -> h0 (f16)
    k_gemm<float><<<dim3(G3 / 128, N_NODES / 128), 256, 0, stream>>>(x, wi0, bias0, gxbuf, N_NODES, G3, IN_DIM);
    k_rec<<<NGRAPH, 512, 0, stream>>>(gxbuf, wsw0, bhh0, starts, h0, (float*)nullptr);
    // layer 1: gx1 = h0*Wih1^T + bias1 (f16 MFMA); rec + masked mean -> out (f32)
    k_gemm<_Float16><<<dim3(G3 / 128, N_NODES / 128), 256, 0, stream>>>((const _Float16*)h0, wi1, bias1, gxbuf, N_NODES, G3, HIDDEN);
    k_rec<<<NGRAPH, 512, 0, stream>>>(gxbuf, wsw1, bhh1, starts, (u16*)nullptr, out);
}